// Round 15
// baseline (103.867 us; speedup 1.0000x reference)
//
#include <hip/hip_runtime.h>

// Problem constants
#define B_   64
#define M_   256
#define D_   256
#define A_   18
#define E_   4
#define S_   64
#define ES_  256          // E_*S_ == M_
#define H_   512
#define K2_  (A_*D_)      // 4608

typedef _Float16 f16;
typedef _Float16 f16x4 __attribute__((ext_vector_type(4)));
typedef _Float16 f16x8 __attribute__((ext_vector_type(8)));
typedef float    f32x4 __attribute__((ext_vector_type(4)));

static __device__ __forceinline__ f16x8 cat8(f16x4 a, f16x4 b) {
  return __builtin_shufflevector(a, b, 0, 1, 2, 3, 4, 5, 6, 7);
}
static __device__ __forceinline__ f16x8 pack8(float4 u0, float4 u1) {
  f16x8 a;
  a[0] = (f16)u0.x; a[1] = (f16)u0.y; a[2] = (f16)u0.z; a[3] = (f16)u0.w;
  a[4] = (f16)u1.x; a[5] = (f16)u1.y; a[6] = (f16)u1.z; a[7] = (f16)u1.w;
  return a;
}

// ===========================================================================
// k_preplog: ONE launch = all conversions + logits/exp/partial-sums.
// Block ranges:
//   [0,1024)      obs fp32 [b][M][D] -> obsT16 [b][D][M]
//   [1024,1152)   w1 -> w1T   (per-e 256x512 -> 512x256)
//   [1152,3456)   w2 -> w2T   (per-e 512x4608 -> 4608x512)
//   [3456]        action rank-sort -> order
//   [3457,4481)   logits: exp16/expT16/rowpart/colpart (stages phi^T itself)
// ===========================================================================
__global__ __launch_bounds__(256) void k_preplog(
    const float* __restrict__ obs, const float* __restrict__ phi,
    const float* __restrict__ w1, const float* __restrict__ w2,
    const int* __restrict__ action,
    f16* __restrict__ obsT16, f16* __restrict__ w1T, f16* __restrict__ w2T,
    int* __restrict__ order,
    f16* __restrict__ exp16, f16* __restrict__ expT16,
    float* __restrict__ rowpart, float* __restrict__ colpart)
{
  __shared__ f16 Bs[64][264];                       // 33.8 KB
  f16 (*T)[68] = reinterpret_cast<f16(*)[68]>(&Bs[0][0]);  // alias (8.7 KB)
  const int bx = blockIdx.x;
  const int t  = threadIdx.x;

  if (bx < 3456) {
    // ---------------- transpose+convert tile ----------------
    const int rr = t >> 4, cc = (t & 15) * 4;
    const float* src; f16* dst; int R, C, r0, c0;
    if (bx < 1024) {
      const int x = bx & 3, y = (bx >> 2) & 3, z = bx >> 4;
      src = obs + (long)z * (M_ * D_); dst = obsT16 + (long)z * (M_ * D_);
      R = M_; C = D_; r0 = y * 64; c0 = x * 64;
    } else if (bx < 1152) {
      const int idx = bx - 1024;
      const int x = idx & 7, y = (idx >> 3) & 3, z = idx >> 5;
      src = w1 + (long)z * (D_ * H_); dst = w1T + (long)z * (H_ * D_);
      R = D_; C = H_; r0 = y * 64; c0 = x * 64;
    } else {
      const int idx = bx - 1152;
      const int x = idx % 72, rem = idx / 72, y = rem & 7, z = rem >> 3;
      src = w2 + (long)z * ((long)H_ * K2_); dst = w2T + (long)z * ((long)K2_ * H_);
      R = H_; C = K2_; r0 = y * 64; c0 = x * 64;
    }
#pragma unroll
    for (int p = 0; p < 4; ++p) {
      const int row = rr + p * 16;
      const float4 v = *reinterpret_cast<const float4*>(
          &src[(long)(r0 + row) * C + c0 + cc]);
      T[row][cc + 0] = (f16)v.x; T[row][cc + 1] = (f16)v.y;
      T[row][cc + 2] = (f16)v.z; T[row][cc + 3] = (f16)v.w;
    }
    __syncthreads();
#pragma unroll
    for (int p = 0; p < 4; ++p) {
      const int oc = rr + p * 16;
      f16x4 g;
#pragma unroll
      for (int i = 0; i < 4; ++i) g[i] = T[cc + i][oc];
      *reinterpret_cast<f16x4*>(&dst[(long)(c0 + oc) * R + r0 + cc]) = g;
    }
    return;
  }

  if (bx == 3456) {
    // ---------------- action rank-sort ----------------
    if (t < B_) {
      const int a = action[t];
      int rank = 0;
#pragma unroll 8
      for (int i = 0; i < B_; ++i) {
        const int ai = action[i];
        rank += (ai < a) || (ai == a && i < t);
      }
      order[rank] = t;
    }
    return;
  }

  // ---------------- logits + exp + partial sums ----------------
  const int lb  = bx - 3457;
  const int es0 = (lb & 3) * 64, m0g = ((lb >> 2) & 3) * 64;
  const int bz  = lb >> 4;
  const long bo = (long)bz * (M_ * D_);
  const long bb = (long)bz * (M_ * ES_);

  // stage phi^T slice into Bs[es][d]  (coalesced along es)
  {
    const int el = t & 63, wg = t >> 6;
#pragma unroll
    for (int dp = 0; dp < D_; dp += 32) {
      f16x8 hv;
#pragma unroll
      for (int j = 0; j < 8; ++j)
        hv[j] = (f16)phi[(long)(dp + wg * 8 + j) * ES_ + es0 + el];
      *reinterpret_cast<f16x8*>(&Bs[el][dp + wg * 8]) = hv;
    }
  }
  __syncthreads();

  const int w = t >> 6, lane = t & 63;
  const int wr = w >> 1, wc = w & 1;
  const int lr = lane & 15, lk = (lane >> 4) * 8;
  const int orow = (lane >> 4) * 4;

  f32x4 acc[2][2] = {};
  const float* Ap = obs + bo + (long)(m0g + wr * 32 + lr) * D_ + lk;
#pragma unroll
  for (int k0 = 0; k0 < D_; k0 += 32) {
    const float4 u00 = *reinterpret_cast<const float4*>(Ap + k0);
    const float4 u01 = *reinterpret_cast<const float4*>(Ap + k0 + 4);
    const float4 u10 = *reinterpret_cast<const float4*>(Ap + 16 * D_ + k0);
    const float4 u11 = *reinterpret_cast<const float4*>(Ap + 16 * D_ + k0 + 4);
    const f16x8 a0 = pack8(u00, u01);
    const f16x8 a1 = pack8(u10, u11);
    const f16x8 b0 = *reinterpret_cast<const f16x8*>(&Bs[wc * 32 + lr][k0 + lk]);
    const f16x8 b1 = *reinterpret_cast<const f16x8*>(&Bs[wc * 32 + 16 + lr][k0 + lk]);
    acc[0][0] = __builtin_amdgcn_mfma_f32_16x16x32_f16(a0, b0, acc[0][0], 0, 0, 0);
    acc[0][1] = __builtin_amdgcn_mfma_f32_16x16x32_f16(a0, b1, acc[0][1], 0, 0, 0);
    acc[1][0] = __builtin_amdgcn_mfma_f32_16x16x32_f16(a1, b0, acc[1][0], 0, 0, 0);
    acc[1][1] = __builtin_amdgcn_mfma_f32_16x16x32_f16(a1, b1, acc[1][1], 0, 0, 0);
  }
  __syncthreads();   // Bs dead; reuse as T

#pragma unroll
  for (int fi = 0; fi < 2; ++fi)
#pragma unroll
    for (int fj = 0; fj < 2; ++fj) {
      const int gm = wr * 32 + fi * 16 + orow;
      const int gn = wc * 32 + fj * 16 + lr;
#pragma unroll
      for (int r = 0; r < 4; ++r)
        T[gm + r][gn] = (f16)__expf(acc[fi][fj][r]);
    }
  __syncthreads();

  {  // exp16 [m][es]
    const int row = t >> 2, q = t & 3;
    f16x4 p0 = *reinterpret_cast<const f16x4*>(&T[row][q * 16 + 0]);
    f16x4 p1 = *reinterpret_cast<const f16x4*>(&T[row][q * 16 + 4]);
    f16x4 p2 = *reinterpret_cast<const f16x4*>(&T[row][q * 16 + 8]);
    f16x4 p3 = *reinterpret_cast<const f16x4*>(&T[row][q * 16 + 12]);
    f16* dst = exp16 + bb + (long)(m0g + row) * ES_ + es0 + q * 16;
    *reinterpret_cast<f16x8*>(dst)     = cat8(p0, p1);
    *reinterpret_cast<f16x8*>(dst + 8) = cat8(p2, p3);
  }
  {  // expT16 [es][m]
    const int er = t >> 2, q = t & 3;
    f16x4 g[4];
#pragma unroll
    for (int j = 0; j < 4; ++j)
#pragma unroll
      for (int i = 0; i < 4; ++i)
        g[j][i] = T[q * 16 + j * 4 + i][er];
    f16* dst = expT16 + bb + (long)(es0 + er) * M_ + m0g + q * 16;
    *reinterpret_cast<f16x8*>(dst)     = cat8(g[0], g[1]);
    *reinterpret_cast<f16x8*>(dst + 8) = cat8(g[2], g[3]);
  }
  if (t < 64) {
    float s = 0.f;
#pragma unroll
    for (int i = 0; i < 16; ++i) {
      const f16x4 v = *reinterpret_cast<const f16x4*>(&T[t][i * 4]);
      s += (float)v[0] + (float)v[1] + (float)v[2] + (float)v[3];
    }
    rowpart[((long)bz * 256 + m0g + t) * 4 + (lb & 3)] = s;
  } else if (t < 128) {
    const int es = t - 64;
    float s = 0.f;
#pragma unroll
    for (int i = 0; i < 64; ++i) s += (float)T[i][es];
    colpart[((long)bz * 256 + es0 + es) * 4 + ((lb >> 2) & 3)] = s;
  }
}

// ===========================================================================
// k_hy5: fused slots->h->y per (b,e,half-of-s). 512 blocks, 512 threads.
// R14: explicit deep register prefetch (circular frag queues, static indices)
// in all three GEMMs — attacks the latency-boundness diagnosed in R13
// (VGPR_Count=56 showed the compiler pipelined depth~1; 900-cyc cold-HBM
// loads were serialized against MFMAs).
//  GEMM0: depth-4 A+B queues (16 loads upfront)
//  GEMM1: depth-4 B queue, preloaded before GEMM0's epilogue/barrier
//  GEMM2: depth-8 B queue, preloaded right after GEMM1's MFMA loop
// ===========================================================================
#define SPAD 264   // 256 + 8
#define HPAD2 520  // 512 + 8
#define MFMA16(a, b, c) __builtin_amdgcn_mfma_f32_16x16x32_f16(a, b, c, 0, 0, 0)

__global__ __launch_bounds__(512, 4) void k_hy5(
    const f16* __restrict__ expT16, const f16* __restrict__ obsT16,
    const float* __restrict__ colpart,
    const f16* __restrict__ w1T, const float* __restrict__ b1,
    const f16* __restrict__ w2T, const float* __restrict__ b2,
    const int* __restrict__ action, const int* __restrict__ order,
    f16* __restrict__ yT16)
{
  __shared__ f16 ss[32][SPAD];
  __shared__ f16 hs[32][HPAD2];
  const int bx = blockIdx.x;
  const int L  = (bx & 7) * 64 + (bx >> 3);   // bijective, 512 % 8 == 0
  const int e = L >> 7, sb = (L >> 1) & 63, half = L & 1;
  const int b = order[sb];
  const int s0 = half * 32;
  int a = action[b];
  a = (a < 0) ? 0 : (a >= A_ ? A_ - 1 : a);

  const int t = threadIdx.x, w = t >> 6, lane = t & 63;
  const int lr = lane & 15, lk = (lane >> 4) * 8;
  const int orow = (lane >> 4) * 4;

  const int n0_2 = w * 32;
  const f16* Bp2 = w2T + (long)e * ((long)K2_ * H_)
                 + ((long)a * D_ + n0_2 + lr) * H_ + lk;
  const f16* Bp1 = w1T + (long)e * (H_ * D_) + (long)(w * 64 + lr) * D_ + lk;

  // ---- GEMM0: ss[32][256] = (1/colsum) * expT @ obsT^T  (depth-4 queues) --
  {
    const int n0 = w * 32;
    f32x4 acc00 = {}, acc01 = {}, acc10 = {}, acc11 = {};
    const f16* Ap = expT16 + (long)b * (ES_ * M_)
                  + (long)(e * S_ + s0 + lr) * M_ + lk;
    const f16* Bp = obsT16 + (long)b * (D_ * M_) + (long)(n0 + lr) * M_ + lk;

    f16x8 aq0[4], aq1[4], bq0[4], bq1[4];
#pragma unroll
    for (int p = 0; p < 4; ++p) {
      aq0[p] = *reinterpret_cast<const f16x8*>(Ap + p * 32);
      aq1[p] = *reinterpret_cast<const f16x8*>(Ap + 16 * M_ + p * 32);
      bq0[p] = *reinterpret_cast<const f16x8*>(Bp + p * 32);
      bq1[p] = *reinterpret_cast<const f16x8*>(Bp + 16 * M_ + p * 32);
    }
#pragma unroll
    for (int it = 0; it < 8; ++it) {
      const int c = it & 3;
      const f16x8 a0 = aq0[c], a1 = aq1[c], b0 = bq0[c], b1f = bq1[c];
      if (it < 4) {
        const int k = (it + 4) * 32;
        aq0[c] = *reinterpret_cast<const f16x8*>(Ap + k);
        aq1[c] = *reinterpret_cast<const f16x8*>(Ap + 16 * M_ + k);
        bq0[c] = *reinterpret_cast<const f16x8*>(Bp + k);
        bq1[c] = *reinterpret_cast<const f16x8*>(Bp + 16 * M_ + k);
      }
      acc00 = MFMA16(a0, b0, acc00); acc01 = MFMA16(a0, b1f, acc01);
      acc10 = MFMA16(a1, b0, acc10); acc11 = MFMA16(a1, b1f, acc11);
    }

    // preload GEMM1's first 4 k-steps of B (independent of ss/barrier)
    f16x8 bq1g[4][4];
#pragma unroll
    for (int p = 0; p < 4; ++p)
#pragma unroll
      for (int fj = 0; fj < 4; ++fj)
        bq1g[p][fj] = *reinterpret_cast<const f16x8*>(
            Bp1 + (long)fj * 16 * D_ + p * 32);

    // GEMM0 epilogue -> ss
    f32x4 accs[2][2] = {{acc00, acc01}, {acc10, acc11}};
#pragma unroll
    for (int fi = 0; fi < 2; ++fi) {
      float inv[4];
#pragma unroll
      for (int r = 0; r < 4; ++r) {
        const int ges = e * S_ + s0 + fi * 16 + orow + r;
        const float4 cp = *reinterpret_cast<const float4*>(
            &colpart[((long)b * 256 + ges) * 4]);
        inv[r] = 1.0f / (cp.x + cp.y + cp.z + cp.w);
      }
#pragma unroll
      for (int fj = 0; fj < 2; ++fj) {
        const int gm = fi * 16 + orow;
        const int gn = n0 + fj * 16 + lr;
#pragma unroll
        for (int r = 0; r < 4; ++r)
          ss[gm + r][gn] = (f16)(accs[fi][fj][r] * inv[r]);
      }
    }
    __syncthreads();

    // ---- GEMM1: hs[32][512] = relu(ss @ w1T[e]^T + b1)  (depth-4 B) -------
    {
      const int n1 = w * 64;
      f32x4 acc[2][4] = {};
#pragma unroll
      for (int it = 0; it < 8; ++it) {
        const int c = it & 3;
        f16x8 bf[4];
#pragma unroll
        for (int fj = 0; fj < 4; ++fj) bf[fj] = bq1g[c][fj];
        if (it < 4) {
          const int k = (it + 4) * 32;
#pragma unroll
          for (int fj = 0; fj < 4; ++fj)
            bq1g[c][fj] = *reinterpret_cast<const f16x8*>(
                Bp1 + (long)fj * 16 * D_ + k);
        }
        f16x8 af[2];
#pragma unroll
        for (int fi = 0; fi < 2; ++fi)
          af[fi] = *reinterpret_cast<const f16x8*>(&ss[fi * 16 + lr][it * 32 + lk]);
#pragma unroll
        for (int fi = 0; fi < 2; ++fi)
#pragma unroll
          for (int fj = 0; fj < 4; ++fj)
            acc[fi][fj] = MFMA16(af[fi], bf[fj], acc[fi][fj]);
      }

      // preload GEMM2's first 8 k-steps of B (16 loads) — fly during epilogue
      f16x8 bq2a[8], bq2b[8];
#pragma unroll
      for (int p = 0; p < 8; ++p) {
        bq2a[p] = *reinterpret_cast<const f16x8*>(Bp2 + p * 32);
        bq2b[p] = *reinterpret_cast<const f16x8*>(Bp2 + 16 * H_ + p * 32);
      }

      // GEMM1 epilogue -> hs
#pragma unroll
      for (int fi = 0; fi < 2; ++fi)
#pragma unroll
        for (int fj = 0; fj < 4; ++fj) {
          const int gm = fi * 16 + orow;
          const int gn = n1 + fj * 16 + lr;
          const float bv = b1[e * H_ + gn];
#pragma unroll
          for (int r = 0; r < 4; ++r)
            hs[gm + r][gn] = (f16)fmaxf(acc[fi][fj][r] + bv, 0.f);
        }
      __syncthreads();

      // ---- GEMM2: y[32 s][32 d/wave] = hs @ w2T[a-slice]^T + b2 (depth-8) -
      {
        f32x4 acc2[2][2] = {};
#pragma unroll
        for (int it = 0; it < 16; ++it) {
          const int c = it & 7;
          const f16x8 b0 = bq2a[c], b1f = bq2b[c];
          if (it < 8) {
            const int k = (it + 8) * 32;
            bq2a[c] = *reinterpret_cast<const f16x8*>(Bp2 + k);
            bq2b[c] = *reinterpret_cast<const f16x8*>(Bp2 + 16 * H_ + k);
          }
          f16x8 af[2];
#pragma unroll
          for (int fi = 0; fi < 2; ++fi)
            af[fi] = *reinterpret_cast<const f16x8*>(&hs[fi * 16 + lr][it * 32 + lk]);
          acc2[0][0] = MFMA16(af[0], b0,  acc2[0][0]);
          acc2[0][1] = MFMA16(af[0], b1f, acc2[0][1]);
          acc2[1][0] = MFMA16(af[1], b0,  acc2[1][0]);
          acc2[1][1] = MFMA16(af[1], b1f, acc2[1][1]);
        }
        // transposed write: yT16[b][d][es = e*64 + s0 + s]
#pragma unroll
        for (int fi = 0; fi < 2; ++fi)
#pragma unroll
          for (int fj = 0; fj < 2; ++fj) {
            const int gm = fi * 16 + orow;           // s within slice
            const int gn = n0_2 + fj * 16 + lr;      // d
            const float bv = b2[e * K2_ + a * D_ + gn];
            f16x4 h4;
#pragma unroll
            for (int r = 0; r < 4; ++r) h4[r] = (f16)(acc2[fi][fj][r] + bv);
            *reinterpret_cast<f16x4*>(
                &yT16[(long)b * (D_ * ES_) + (long)gn * ES_ + e * S_ + s0 + gm]) = h4;
          }
      }
    }
  }
}

// ===========================================================================
// k_out_s: out[b][m][d] (fp32) = (1/rowsum[m]) * exp16[b] @ yT16[b]^T
// grid (4 d, 4 m, 64 b), 256 threads
// ===========================================================================
__global__ __launch_bounds__(256) void k_out_s(
    const f16* __restrict__ exp16, const f16* __restrict__ yT16,
    const float* __restrict__ rowpart, float* __restrict__ out)
{
  const int t = threadIdx.x;
  const int w = t >> 6, lane = t & 63;
  const int wr = w >> 1, wc = w & 1;
  const int m0 = blockIdx.y * 64 + wr * 32;
  const int n0 = blockIdx.x * 64 + wc * 32;
  const int lr = lane & 15, lk = (lane >> 4) * 8;
  const long b = blockIdx.z;

  f32x4 acc[2][2] = {};
  const f16* Ap = exp16 + b * (M_ * ES_) + (long)(m0 + lr) * ES_ + lk;
  const f16* Bp = yT16 + b * (D_ * ES_) + (long)(n0 + lr) * ES_ + lk;
#pragma unroll
  for (int k0 = 0; k0 < ES_; k0 += 32) {
    const f16x8 a0 = *reinterpret_cast<const f16x8*>(Ap + k0);
    const f16x8 a1 = *reinterpret_cast<const f16x8*>(Ap + 16 * ES_ + k0);
    const f16x8 b0 = *reinterpret_cast<const f16x8*>(Bp + k0);
    const f16x8 b1 = *reinterpret_cast<const f16x8*>(Bp + 16 * ES_ + k0);
    acc[0][0] = __builtin_amdgcn_mfma_f32_16x16x32_f16(a0, b0, acc[0][0], 0, 0, 0);
    acc[0][1] = __builtin_amdgcn_mfma_f32_16x16x32_f16(a0, b1, acc[0][1], 0, 0, 0);
    acc[1][0] = __builtin_amdgcn_mfma_f32_16x16x32_f16(a1, b0, acc[1][0], 0, 0, 0);
    acc[1][1] = __builtin_amdgcn_mfma_f32_16x16x32_f16(a1, b1, acc[1][1], 0, 0, 0);
  }

  const int orow = (lane >> 4) * 4;
  float* C = out + b * (M_ * D_);
#pragma unroll
  for (int fi = 0; fi < 2; ++fi) {
    float inv[4];
#pragma unroll
    for (int r = 0; r < 4; ++r) {
      const int gm = m0 + fi * 16 + orow + r;
      const float4 rp = *reinterpret_cast<const float4*>(&rowpart[((long)b * 256 + gm) * 4]);
      inv[r] = 1.0f / (rp.x + rp.y + rp.z + rp.w);
    }
#pragma unroll
    for (int fj = 0; fj < 2; ++fj) {
      const int gm = m0 + fi * 16 + orow;
      const int gn = n0 + fj * 16 + lr;
#pragma unroll
      for (int r = 0; r < 4; ++r)
        C[(long)(gm + r) * D_ + gn] = acc[fi][fj][r] * inv[r];
    }
  }
}

// ===========================================================================
extern "C" void kernel_launch(void* const* d_in, const int* in_sizes, int n_in,
                              void* d_out, int out_size, void* d_ws, size_t ws_size,
                              hipStream_t stream)
{
  const float* obs    = (const float*)d_in[0];
  const int*   action = (const int*)d_in[1];
  const float* phi    = (const float*)d_in[2];
  const float* w1     = (const float*)d_in[3];
  const float* b1     = (const float*)d_in[4];
  const float* w2     = (const float*)d_in[5];
  const float* b2     = (const float*)d_in[6];
  float*       out    = (float*)d_out;

  // Workspace (f16 units), ~54 MB total
  f16* ws = (f16*)d_ws;
  f16* obsT16  = ws + 0;          //  4,194,304
  f16* w1T     = ws + 4194304;    //    524,288
  f16* w2T     = ws + 4718592;    //  9,437,184
  f16* exp16   = ws + 14155776;   //  4,194,304
  f16* expT16  = ws + 18350080;   //  4,194,304
  f16* yT16    = ws + 22544384;   //  4,194,304
  float* rowpart = (float*)(ws + 26738688);   // 65,536 f32
  float* colpart = (float*)(ws + 26869760);   // 65,536 f32
  int*   order   = (int*)(ws + 27000832);     // 64 ints

  k_preplog<<<dim3(4481),     256, 0, stream>>>(obs, phi, w1, w2, action,
                                                obsT16, w1T, w2T, order,
                                                exp16, expT16, rowpart, colpart);
  k_hy5    <<<dim3(512),      512, 0, stream>>>(expT16, obsT16, colpart,
                                                w1T, b1, w2T, b2,
                                                action, order, yT16);
  k_out_s  <<<dim3(4, 4, 64), 256, 0, stream>>>(exp16, yT16, rowpart, out);
}

// Round 16
// 103.412 us; speedup vs baseline: 1.0044x; 1.0044x over previous
//
#include <hip/hip_runtime.h>

// Problem constants
#define B_   64
#define M_   256
#define D_   256
#define A_   18
#define E_   4
#define S_   64
#define ES_  256          // E_*S_ == M_
#define H_   512
#define K2_  (A_*D_)      // 4608

typedef _Float16 f16;
typedef _Float16 f16x4 __attribute__((ext_vector_type(4)));
typedef _Float16 f16x8 __attribute__((ext_vector_type(8)));
typedef float    f32x4 __attribute__((ext_vector_type(4)));

static __device__ __forceinline__ f16x8 cat8(f16x4 a, f16x4 b) {
  return __builtin_shufflevector(a, b, 0, 1, 2, 3, 4, 5, 6, 7);
}
static __device__ __forceinline__ f16x8 pack8(float4 u0, float4 u1) {
  f16x8 a;
  a[0] = (f16)u0.x; a[1] = (f16)u0.y; a[2] = (f16)u0.z; a[3] = (f16)u0.w;
  a[4] = (f16)u1.x; a[5] = (f16)u1.y; a[6] = (f16)u1.z; a[7] = (f16)u1.w;
  return a;
}

// ===========================================================================
// k_preplog: ONE launch = all conversions + logits/exp/partial-sums.
// Block ranges:
//   [0,1024)      obs fp32 [b][M][D] -> obsT16 [b][D][M]
//   [1024,1152)   w1 -> w1T   (per-e 256x512 -> 512x256)
//   [1152,3456)   w2 -> w2T   (per-e 512x4608 -> 4608x512)
//   [3456]        action rank-sort -> order
//   [3457,4481)   logits: exp16/expT16/rowpart/colpart (stages phi^T itself)
// ===========================================================================
__global__ __launch_bounds__(256) void k_preplog(
    const float* __restrict__ obs, const float* __restrict__ phi,
    const float* __restrict__ w1, const float* __restrict__ w2,
    const int* __restrict__ action,
    f16* __restrict__ obsT16, f16* __restrict__ w1T, f16* __restrict__ w2T,
    int* __restrict__ order,
    f16* __restrict__ exp16, f16* __restrict__ expT16,
    float* __restrict__ rowpart, float* __restrict__ colpart)
{
  __shared__ f16 Bs[64][264];                       // 33.8 KB
  f16 (*T)[68] = reinterpret_cast<f16(*)[68]>(&Bs[0][0]);  // alias (8.7 KB)
  const int bx = blockIdx.x;
  const int t  = threadIdx.x;

  if (bx < 3456) {
    // ---------------- transpose+convert tile ----------------
    const int rr = t >> 4, cc = (t & 15) * 4;
    const float* src; f16* dst; int R, C, r0, c0;
    if (bx < 1024) {
      const int x = bx & 3, y = (bx >> 2) & 3, z = bx >> 4;
      src = obs + (long)z * (M_ * D_); dst = obsT16 + (long)z * (M_ * D_);
      R = M_; C = D_; r0 = y * 64; c0 = x * 64;
    } else if (bx < 1152) {
      const int idx = bx - 1024;
      const int x = idx & 7, y = (idx >> 3) & 3, z = idx >> 5;
      src = w1 + (long)z * (D_ * H_); dst = w1T + (long)z * (H_ * D_);
      R = D_; C = H_; r0 = y * 64; c0 = x * 64;
    } else {
      const int idx = bx - 1152;
      const int x = idx % 72, rem = idx / 72, y = rem & 7, z = rem >> 3;
      src = w2 + (long)z * ((long)H_ * K2_); dst = w2T + (long)z * ((long)K2_ * H_);
      R = H_; C = K2_; r0 = y * 64; c0 = x * 64;
    }
#pragma unroll
    for (int p = 0; p < 4; ++p) {
      const int row = rr + p * 16;
      const float4 v = *reinterpret_cast<const float4*>(
          &src[(long)(r0 + row) * C + c0 + cc]);
      T[row][cc + 0] = (f16)v.x; T[row][cc + 1] = (f16)v.y;
      T[row][cc + 2] = (f16)v.z; T[row][cc + 3] = (f16)v.w;
    }
    __syncthreads();
#pragma unroll
    for (int p = 0; p < 4; ++p) {
      const int oc = rr + p * 16;
      f16x4 g;
#pragma unroll
      for (int i = 0; i < 4; ++i) g[i] = T[cc + i][oc];
      *reinterpret_cast<f16x4*>(&dst[(long)(c0 + oc) * R + r0 + cc]) = g;
    }
    return;
  }

  if (bx == 3456) {
    // ---------------- action rank-sort ----------------
    if (t < B_) {
      const int a = action[t];
      int rank = 0;
#pragma unroll 8
      for (int i = 0; i < B_; ++i) {
        const int ai = action[i];
        rank += (ai < a) || (ai == a && i < t);
      }
      order[rank] = t;
    }
    return;
  }

  // ---------------- logits + exp + partial sums ----------------
  const int lb  = bx - 3457;
  const int es0 = (lb & 3) * 64, m0g = ((lb >> 2) & 3) * 64;
  const int bz  = lb >> 4;
  const long bo = (long)bz * (M_ * D_);
  const long bb = (long)bz * (M_ * ES_);

  // stage phi^T slice into Bs[es][d]  (coalesced along es)
  {
    const int el = t & 63, wg = t >> 6;
#pragma unroll
    for (int dp = 0; dp < D_; dp += 32) {
      f16x8 hv;
#pragma unroll
      for (int j = 0; j < 8; ++j)
        hv[j] = (f16)phi[(long)(dp + wg * 8 + j) * ES_ + es0 + el];
      *reinterpret_cast<f16x8*>(&Bs[el][dp + wg * 8]) = hv;
    }
  }
  __syncthreads();

  const int w = t >> 6, lane = t & 63;
  const int wr = w >> 1, wc = w & 1;
  const int lr = lane & 15, lk = (lane >> 4) * 8;
  const int orow = (lane >> 4) * 4;

  f32x4 acc[2][2] = {};
  const float* Ap = obs + bo + (long)(m0g + wr * 32 + lr) * D_ + lk;
#pragma unroll
  for (int k0 = 0; k0 < D_; k0 += 32) {
    const float4 u00 = *reinterpret_cast<const float4*>(Ap + k0);
    const float4 u01 = *reinterpret_cast<const float4*>(Ap + k0 + 4);
    const float4 u10 = *reinterpret_cast<const float4*>(Ap + 16 * D_ + k0);
    const float4 u11 = *reinterpret_cast<const float4*>(Ap + 16 * D_ + k0 + 4);
    const f16x8 a0 = pack8(u00, u01);
    const f16x8 a1 = pack8(u10, u11);
    const f16x8 b0 = *reinterpret_cast<const f16x8*>(&Bs[wc * 32 + lr][k0 + lk]);
    const f16x8 b1 = *reinterpret_cast<const f16x8*>(&Bs[wc * 32 + 16 + lr][k0 + lk]);
    acc[0][0] = __builtin_amdgcn_mfma_f32_16x16x32_f16(a0, b0, acc[0][0], 0, 0, 0);
    acc[0][1] = __builtin_amdgcn_mfma_f32_16x16x32_f16(a0, b1, acc[0][1], 0, 0, 0);
    acc[1][0] = __builtin_amdgcn_mfma_f32_16x16x32_f16(a1, b0, acc[1][0], 0, 0, 0);
    acc[1][1] = __builtin_amdgcn_mfma_f32_16x16x32_f16(a1, b1, acc[1][1], 0, 0, 0);
  }
  __syncthreads();   // Bs dead; reuse as T

#pragma unroll
  for (int fi = 0; fi < 2; ++fi)
#pragma unroll
    for (int fj = 0; fj < 2; ++fj) {
      const int gm = wr * 32 + fi * 16 + orow;
      const int gn = wc * 32 + fj * 16 + lr;
#pragma unroll
      for (int r = 0; r < 4; ++r)
        T[gm + r][gn] = (f16)__expf(acc[fi][fj][r]);
    }
  __syncthreads();

  {  // exp16 [m][es]
    const int row = t >> 2, q = t & 3;
    f16x4 p0 = *reinterpret_cast<const f16x4*>(&T[row][q * 16 + 0]);
    f16x4 p1 = *reinterpret_cast<const f16x4*>(&T[row][q * 16 + 4]);
    f16x4 p2 = *reinterpret_cast<const f16x4*>(&T[row][q * 16 + 8]);
    f16x4 p3 = *reinterpret_cast<const f16x4*>(&T[row][q * 16 + 12]);
    f16* dst = exp16 + bb + (long)(m0g + row) * ES_ + es0 + q * 16;
    *reinterpret_cast<f16x8*>(dst)     = cat8(p0, p1);
    *reinterpret_cast<f16x8*>(dst + 8) = cat8(p2, p3);
  }
  {  // expT16 [es][m]
    const int er = t >> 2, q = t & 3;
    f16x4 g[4];
#pragma unroll
    for (int j = 0; j < 4; ++j)
#pragma unroll
      for (int i = 0; i < 4; ++i)
        g[j][i] = T[q * 16 + j * 4 + i][er];
    f16* dst = expT16 + bb + (long)(es0 + er) * M_ + m0g + q * 16;
    *reinterpret_cast<f16x8*>(dst)     = cat8(g[0], g[1]);
    *reinterpret_cast<f16x8*>(dst + 8) = cat8(g[2], g[3]);
  }
  if (t < 64) {
    float s = 0.f;
#pragma unroll
    for (int i = 0; i < 16; ++i) {
      const f16x4 v = *reinterpret_cast<const f16x4*>(&T[t][i * 4]);
      s += (float)v[0] + (float)v[1] + (float)v[2] + (float)v[3];
    }
    rowpart[((long)bz * 256 + m0g + t) * 4 + (lb & 3)] = s;
  } else if (t < 128) {
    const int es = t - 64;
    float s = 0.f;
#pragma unroll
    for (int i = 0; i < 64; ++i) s += (float)T[i][es];
    colpart[((long)bz * 256 + es0 + es) * 4 + ((lb >> 2) & 3)] = s;
  }
}

// ===========================================================================
// k_hy5: fused slots->h->y per (b,e,half-of-s). 512 blocks, 512 threads.
// R14: explicit deep register prefetch (circular frag queues, static indices)
// in all three GEMMs — attacks the latency-boundness diagnosed in R13
// (VGPR_Count=56 showed the compiler pipelined depth~1; 900-cyc cold-HBM
// loads were serialized against MFMAs).
//  GEMM0: depth-4 A+B queues (16 loads upfront)
//  GEMM1: depth-4 B queue, preloaded before GEMM0's epilogue/barrier
//  GEMM2: depth-8 B queue, preloaded right after GEMM1's MFMA loop
// ===========================================================================
#define SPAD 264   // 256 + 8
#define HPAD2 520  // 512 + 8
#define MFMA16(a, b, c) __builtin_amdgcn_mfma_f32_16x16x32_f16(a, b, c, 0, 0, 0)

__global__ __launch_bounds__(512, 4) void k_hy5(
    const f16* __restrict__ expT16, const f16* __restrict__ obsT16,
    const float* __restrict__ colpart,
    const f16* __restrict__ w1T, const float* __restrict__ b1,
    const f16* __restrict__ w2T, const float* __restrict__ b2,
    const int* __restrict__ action, const int* __restrict__ order,
    f16* __restrict__ yT16)
{
  __shared__ f16 ss[32][SPAD];
  __shared__ f16 hs[32][HPAD2];
  const int bx = blockIdx.x;
  const int L  = (bx & 7) * 64 + (bx >> 3);   // bijective, 512 % 8 == 0
  const int e = L >> 7, sb = (L >> 1) & 63, half = L & 1;
  const int b = order[sb];
  const int s0 = half * 32;
  int a = action[b];
  a = (a < 0) ? 0 : (a >= A_ ? A_ - 1 : a);

  const int t = threadIdx.x, w = t >> 6, lane = t & 63;
  const int lr = lane & 15, lk = (lane >> 4) * 8;
  const int orow = (lane >> 4) * 4;

  const int n0_2 = w * 32;
  const f16* Bp2 = w2T + (long)e * ((long)K2_ * H_)
                 + ((long)a * D_ + n0_2 + lr) * H_ + lk;
  const f16* Bp1 = w1T + (long)e * (H_ * D_) + (long)(w * 64 + lr) * D_ + lk;

  // ---- GEMM0: ss[32][256] = (1/colsum) * expT @ obsT^T  (depth-4 queues) --
  {
    const int n0 = w * 32;
    f32x4 acc00 = {}, acc01 = {}, acc10 = {}, acc11 = {};
    const f16* Ap = expT16 + (long)b * (ES_ * M_)
                  + (long)(e * S_ + s0 + lr) * M_ + lk;
    const f16* Bp = obsT16 + (long)b * (D_ * M_) + (long)(n0 + lr) * M_ + lk;

    f16x8 aq0[4], aq1[4], bq0[4], bq1[4];
#pragma unroll
    for (int p = 0; p < 4; ++p) {
      aq0[p] = *reinterpret_cast<const f16x8*>(Ap + p * 32);
      aq1[p] = *reinterpret_cast<const f16x8*>(Ap + 16 * M_ + p * 32);
      bq0[p] = *reinterpret_cast<const f16x8*>(Bp + p * 32);
      bq1[p] = *reinterpret_cast<const f16x8*>(Bp + 16 * M_ + p * 32);
    }
#pragma unroll
    for (int it = 0; it < 8; ++it) {
      const int c = it & 3;
      const f16x8 a0 = aq0[c], a1 = aq1[c], b0 = bq0[c], b1f = bq1[c];
      if (it < 4) {
        const int k = (it + 4) * 32;
        aq0[c] = *reinterpret_cast<const f16x8*>(Ap + k);
        aq1[c] = *reinterpret_cast<const f16x8*>(Ap + 16 * M_ + k);
        bq0[c] = *reinterpret_cast<const f16x8*>(Bp + k);
        bq1[c] = *reinterpret_cast<const f16x8*>(Bp + 16 * M_ + k);
      }
      acc00 = MFMA16(a0, b0, acc00); acc01 = MFMA16(a0, b1f, acc01);
      acc10 = MFMA16(a1, b0, acc10); acc11 = MFMA16(a1, b1f, acc11);
    }

    // preload GEMM1's first 4 k-steps of B (independent of ss/barrier)
    f16x8 bq1g[4][4];
#pragma unroll
    for (int p = 0; p < 4; ++p)
#pragma unroll
      for (int fj = 0; fj < 4; ++fj)
        bq1g[p][fj] = *reinterpret_cast<const f16x8*>(
            Bp1 + (long)fj * 16 * D_ + p * 32);

    // GEMM0 epilogue -> ss
    f32x4 accs[2][2] = {{acc00, acc01}, {acc10, acc11}};
#pragma unroll
    for (int fi = 0; fi < 2; ++fi) {
      float inv[4];
#pragma unroll
      for (int r = 0; r < 4; ++r) {
        const int ges = e * S_ + s0 + fi * 16 + orow + r;
        const float4 cp = *reinterpret_cast<const float4*>(
            &colpart[((long)b * 256 + ges) * 4]);
        inv[r] = 1.0f / (cp.x + cp.y + cp.z + cp.w);
      }
#pragma unroll
      for (int fj = 0; fj < 2; ++fj) {
        const int gm = fi * 16 + orow;
        const int gn = n0 + fj * 16 + lr;
#pragma unroll
        for (int r = 0; r < 4; ++r)
          ss[gm + r][gn] = (f16)(accs[fi][fj][r] * inv[r]);
      }
    }
    __syncthreads();

    // ---- GEMM1: hs[32][512] = relu(ss @ w1T[e]^T + b1)  (depth-4 B) -------
    {
      const int n1 = w * 64;
      f32x4 acc[2][4] = {};
#pragma unroll
      for (int it = 0; it < 8; ++it) {
        const int c = it & 3;
        f16x8 bf[4];
#pragma unroll
        for (int fj = 0; fj < 4; ++fj) bf[fj] = bq1g[c][fj];
        if (it < 4) {
          const int k = (it + 4) * 32;
#pragma unroll
          for (int fj = 0; fj < 4; ++fj)
            bq1g[c][fj] = *reinterpret_cast<const f16x8*>(
                Bp1 + (long)fj * 16 * D_ + k);
        }
        f16x8 af[2];
#pragma unroll
        for (int fi = 0; fi < 2; ++fi)
          af[fi] = *reinterpret_cast<const f16x8*>(&ss[fi * 16 + lr][it * 32 + lk]);
#pragma unroll
        for (int fi = 0; fi < 2; ++fi)
#pragma unroll
          for (int fj = 0; fj < 4; ++fj)
            acc[fi][fj] = MFMA16(af[fi], bf[fj], acc[fi][fj]);
      }

      // preload GEMM2's first 8 k-steps of B (16 loads) — fly during epilogue
      f16x8 bq2a[8], bq2b[8];
#pragma unroll
      for (int p = 0; p < 8; ++p) {
        bq2a[p] = *reinterpret_cast<const f16x8*>(Bp2 + p * 32);
        bq2b[p] = *reinterpret_cast<const f16x8*>(Bp2 + 16 * H_ + p * 32);
      }

      // GEMM1 epilogue -> hs
#pragma unroll
      for (int fi = 0; fi < 2; ++fi)
#pragma unroll
        for (int fj = 0; fj < 4; ++fj) {
          const int gm = fi * 16 + orow;
          const int gn = n1 + fj * 16 + lr;
          const float bv = b1[e * H_ + gn];
#pragma unroll
          for (int r = 0; r < 4; ++r)
            hs[gm + r][gn] = (f16)fmaxf(acc[fi][fj][r] + bv, 0.f);
        }
      __syncthreads();

      // ---- GEMM2: y[32 s][32 d/wave] = hs @ w2T[a-slice]^T + b2 (depth-8) -
      {
        f32x4 acc2[2][2] = {};
#pragma unroll
        for (int it = 0; it < 16; ++it) {
          const int c = it & 7;
          const f16x8 b0 = bq2a[c], b1f = bq2b[c];
          if (it < 8) {
            const int k = (it + 8) * 32;
            bq2a[c] = *reinterpret_cast<const f16x8*>(Bp2 + k);
            bq2b[c] = *reinterpret_cast<const f16x8*>(Bp2 + 16 * H_ + k);
          }
          f16x8 af[2];
#pragma unroll
          for (int fi = 0; fi < 2; ++fi)
            af[fi] = *reinterpret_cast<const f16x8*>(&hs[fi * 16 + lr][it * 32 + lk]);
          acc2[0][0] = MFMA16(af[0], b0,  acc2[0][0]);
          acc2[0][1] = MFMA16(af[0], b1f, acc2[0][1]);
          acc2[1][0] = MFMA16(af[1], b0,  acc2[1][0]);
          acc2[1][1] = MFMA16(af[1], b1f, acc2[1][1]);
        }
        // transposed write: yT16[b][d][es = e*64 + s0 + s]
#pragma unroll
        for (int fi = 0; fi < 2; ++fi)
#pragma unroll
          for (int fj = 0; fj < 2; ++fj) {
            const int gm = fi * 16 + orow;           // s within slice
            const int gn = n0_2 + fj * 16 + lr;      // d
            const float bv = b2[e * K2_ + a * D_ + gn];
            f16x4 h4;
#pragma unroll
            for (int r = 0; r < 4; ++r) h4[r] = (f16)(acc2[fi][fj][r] + bv);
            *reinterpret_cast<f16x4*>(
                &yT16[(long)b * (D_ * ES_) + (long)gn * ES_ + e * S_ + s0 + gm]) = h4;
          }
      }
    }
  }
}

// ===========================================================================
// k_out_s: out[b][m][d] (fp32) = (1/rowsum[m]) * exp16[b] @ yT16[b]^T
// grid (4 d, 4 m, 64 b), 256 threads
// ===========================================================================
__global__ __launch_bounds__(256) void k_out_s(
    const f16* __restrict__ exp16, const f16* __restrict__ yT16,
    const float* __restrict__ rowpart, float* __restrict__ out)
{
  const int t = threadIdx.x;
  const int w = t >> 6, lane = t & 63;
  const int wr = w >> 1, wc = w & 1;
  const int m0 = blockIdx.y * 64 + wr * 32;
  const int n0 = blockIdx.x * 64 + wc * 32;
  const int lr = lane & 15, lk = (lane >> 4) * 8;
  const long b = blockIdx.z;

  f32x4 acc[2][2] = {};
  const f16* Ap = exp16 + b * (M_ * ES_) + (long)(m0 + lr) * ES_ + lk;
  const f16* Bp = yT16 + b * (D_ * ES_) + (long)(n0 + lr) * ES_ + lk;
#pragma unroll
  for (int k0 = 0; k0 < ES_; k0 += 32) {
    const f16x8 a0 = *reinterpret_cast<const f16x8*>(Ap + k0);
    const f16x8 a1 = *reinterpret_cast<const f16x8*>(Ap + 16 * ES_ + k0);
    const f16x8 b0 = *reinterpret_cast<const f16x8*>(Bp + k0);
    const f16x8 b1 = *reinterpret_cast<const f16x8*>(Bp + 16 * ES_ + k0);
    acc[0][0] = __builtin_amdgcn_mfma_f32_16x16x32_f16(a0, b0, acc[0][0], 0, 0, 0);
    acc[0][1] = __builtin_amdgcn_mfma_f32_16x16x32_f16(a0, b1, acc[0][1], 0, 0, 0);
    acc[1][0] = __builtin_amdgcn_mfma_f32_16x16x32_f16(a1, b0, acc[1][0], 0, 0, 0);
    acc[1][1] = __builtin_amdgcn_mfma_f32_16x16x32_f16(a1, b1, acc[1][1], 0, 0, 0);
  }

  const int orow = (lane >> 4) * 4;
  float* C = out + b * (M_ * D_);
#pragma unroll
  for (int fi = 0; fi < 2; ++fi) {
    float inv[4];
#pragma unroll
    for (int r = 0; r < 4; ++r) {
      const int gm = m0 + fi * 16 + orow + r;
      const float4 rp = *reinterpret_cast<const float4*>(&rowpart[((long)b * 256 + gm) * 4]);
      inv[r] = 1.0f / (rp.x + rp.y + rp.z + rp.w);
    }
#pragma unroll
    for (int fj = 0; fj < 2; ++fj) {
      const int gm = m0 + fi * 16 + orow;
      const int gn = n0 + fj * 16 + lr;
#pragma unroll
      for (int r = 0; r < 4; ++r)
        C[(long)(gm + r) * D_ + gn] = acc[fi][fj][r] * inv[r];
    }
  }
}

// ===========================================================================
extern "C" void kernel_launch(void* const* d_in, const int* in_sizes, int n_in,
                              void* d_out, int out_size, void* d_ws, size_t ws_size,
                              hipStream_t stream)
{
  const float* obs    = (const float*)d_in[0];
  const int*   action = (const int*)d_in[1];
  const float* phi    = (const float*)d_in[2];
  const float* w1     = (const float*)d_in[3];
  const float* b1     = (const float*)d_in[4];
  const float* w2     = (const float*)d_in[5];
  const float* b2     = (const float*)d_in[6];
  float*       out    = (float*)d_out;

  // Workspace (f16 units), ~54 MB total
  f16* ws = (f16*)d_ws;
  f16* obsT16  = ws + 0;          //  4,194,304
  f16* w1T     = ws + 4194304;    //    524,288
  f16* w2T     = ws + 4718592;    //  9,437,184
  f16* exp16   = ws + 14155776;   //  4,194,304
  f16* expT16  = ws + 18350080;   //  4,194,304
  f16* yT16    = ws + 22544384;   //  4,194,304
  float* rowpart = (float*)(ws + 26738688);   // 65,536 f32
  float* colpart = (float*)(ws + 26869760);   // 65,536 f32
  int*   order   = (int*)(ws + 27000832);     // 64 ints

  k_preplog<<<dim3(4481),     256, 0, stream>>>(obs, phi, w1, w2, action,
                                                obsT16, w1T, w2T, order,
                                                exp16, expT16, rowpart, colpart);
  k_hy5    <<<dim3(512),      512, 0, stream>>>(expT16, obsT16, colpart,
                                                w1T, b1, w2T, b2,
                                                action, order, yT16);
  k_out_s  <<<dim3(4, 4, 64), 256, 0, stream>>>(exp16, yT16, rowpart, out);
}